// Round 1
// baseline (327.812 us; speedup 1.0000x reference)
//
#include <hip/hip_runtime.h>
#include <math.h>

#define L 4096
#define B 8
#define D 1024
#define NH 16
#define CHUNK 128
#define NC (L / CHUNK)   // 32 chunks
#define BD_STRIDE (B * D) // 8192 floats between consecutive l

// ---------------------------------------------------------------------------
// setup: q[d,n] = 1 - sigmoid(damp)*sigmoid(decay); P[d,n] = sigmoid(damp)*ema*proj*scale
// ---------------------------------------------------------------------------
__global__ void setup_qp(const float* __restrict__ damp,
                         const float* __restrict__ decay,
                         const float* __restrict__ ema,
                         const float* __restrict__ proj,
                         float* __restrict__ q_arr,
                         float* __restrict__ P_arr) {
    int i = blockIdx.x * blockDim.x + threadIdx.x;  // over D*NH = 16384
    if (i >= D * NH) return;
    float p  = 1.0f / (1.0f + expf(-damp[i]));
    float sd = 1.0f / (1.0f + expf(-decay[i]));
    q_arr[i] = 1.0f - p * sd;
    P_arr[i] = p * ema[i] * proj[i] * 0.25f;  // scaling = (1/16)^0.5
}

// ---------------------------------------------------------------------------
// pass1: per (b,d,chunk): run local recurrence with zero init, store end states
// S layout: [b][d][c][n] (n contiguous)
// ---------------------------------------------------------------------------
__global__ void __launch_bounds__(256)
pass1_chunk_end(const float* __restrict__ x,
                const float* __restrict__ q_arr,
                float* __restrict__ S) {
    int d = blockIdx.x * 256 + threadIdx.x;  // 0..1023
    int c = blockIdx.y;                       // 0..31
    int b = blockIdx.z;                       // 0..7

    float q[NH], s[NH];
    const float* qd = q_arr + d * NH;
#pragma unroll
    for (int n = 0; n < NH; n++) { q[n] = qd[n]; s[n] = 0.0f; }

    const float* xp = x + (size_t)c * CHUNK * BD_STRIDE + (size_t)b * D + d;
#pragma unroll 4
    for (int l = 0; l < CHUNK; l++) {
        float xv = xp[(size_t)l * BD_STRIDE];
#pragma unroll
        for (int n = 0; n < NH; n++) s[n] = fmaf(q[n], s[n], xv);
    }

    float* Sp = S + (((size_t)(b * D + d) * NC) + c) * NH;
#pragma unroll
    for (int n = 0; n < NH; n++) Sp[n] = s[n];
}

// ---------------------------------------------------------------------------
// pass2: per (b,d,n): scan 32 chunk end-states with factor q^CHUNK; overwrite
// S in-place with carry-IN state for each chunk (state before chunk start).
// ---------------------------------------------------------------------------
__global__ void __launch_bounds__(256)
pass2_scan(float* __restrict__ S, const float* __restrict__ q_arr) {
    int gid = blockIdx.x * 256 + threadIdx.x;  // B*D*NH = 131072
    if (gid >= B * D * NH) return;
    int n  = gid & (NH - 1);
    int bd = gid >> 4;            // b*D + d
    int d  = bd & (D - 1);

    float q = q_arr[d * NH + n];
    // qc = q^CHUNK = q^128 via 7 squarings
    float qc = q;
#pragma unroll
    for (int i = 0; i < 7; i++) qc *= qc;

    float s = 0.0f;
    float* Sp = S + (size_t)bd * NC * NH + n;
    for (int c = 0; c < NC; c++) {
        float e = Sp[(size_t)c * NH];   // local end-state of chunk c
        Sp[(size_t)c * NH] = s;         // carry-in for chunk c
        s = fmaf(qc, s, e);             // global end-state of chunk c
    }
}

// ---------------------------------------------------------------------------
// pass3: per (b,d,chunk): re-run recurrence from carry-in, project across
// heads, add residual, relu, write out.
// ---------------------------------------------------------------------------
__global__ void __launch_bounds__(256)
pass3_output(const float* __restrict__ x,
             const float* __restrict__ q_arr,
             const float* __restrict__ P_arr,
             const float* __restrict__ rw,
             const float* __restrict__ carry,  // = S, now holding carry-ins
             float* __restrict__ out) {
    int d = blockIdx.x * 256 + threadIdx.x;
    int c = blockIdx.y;
    int b = blockIdx.z;

    float q[NH], P[NH], s[NH];
    const float* qd = q_arr + d * NH;
    const float* Pd = P_arr + d * NH;
    const float* Cp = carry + (((size_t)(b * D + d) * NC) + c) * NH;
#pragma unroll
    for (int n = 0; n < NH; n++) { q[n] = qd[n]; P[n] = Pd[n]; s[n] = Cp[n]; }
    float w = rw[d];

    const float* xp = x   + (size_t)c * CHUNK * BD_STRIDE + (size_t)b * D + d;
    float*       op = out + (size_t)c * CHUNK * BD_STRIDE + (size_t)b * D + d;

#pragma unroll 4
    for (int l = 0; l < CHUNK; l++) {
        float xv = xp[(size_t)l * BD_STRIDE];
        float y  = xv * w;  // residual
#pragma unroll
        for (int n = 0; n < NH; n++) {
            s[n] = fmaf(q[n], s[n], xv);
            y    = fmaf(P[n], s[n], y);
        }
        op[(size_t)l * BD_STRIDE] = fmaxf(y, 0.0f);
    }
}

// ---------------------------------------------------------------------------
extern "C" void kernel_launch(void* const* d_in, const int* in_sizes, int n_in,
                              void* d_out, int out_size, void* d_ws, size_t ws_size,
                              hipStream_t stream) {
    const float* x     = (const float*)d_in[0];
    const float* damp  = (const float*)d_in[1];
    const float* decay = (const float*)d_in[2];
    const float* ema   = (const float*)d_in[3];
    const float* proj  = (const float*)d_in[4];
    const float* rw    = (const float*)d_in[5];
    float* out = (float*)d_out;

    float* q_arr = (float*)d_ws;            // D*NH floats = 64 KB
    float* P_arr = q_arr + D * NH;          // 64 KB
    float* S     = P_arr + D * NH;          // B*D*NC*NH floats = 16.8 MB

    setup_qp<<<(D * NH + 255) / 256, 256, 0, stream>>>(damp, decay, ema, proj, q_arr, P_arr);

    dim3 grid(D / 256, NC, B);
    pass1_chunk_end<<<grid, 256, 0, stream>>>(x, q_arr, S);
    pass2_scan<<<(B * D * NH + 255) / 256, 256, 0, stream>>>(S, q_arr);
    pass3_output<<<grid, 256, 0, stream>>>(x, q_arr, P_arr, rw, S, out);
}

// Round 2
// 313.703 us; speedup vs baseline: 1.0450x; 1.0450x over previous
//
#include <hip/hip_runtime.h>
#include <math.h>

#define L 4096
#define B 8
#define D 1024
#define NH 16
#define CHUNK 64
#define NC (L / CHUNK)    // 64 chunks
#define BD_STRIDE (B * D) // 8192 floats between consecutive l

__device__ __forceinline__ float sigmoidf(float v) {
    return 1.0f / (1.0f + __expf(-v));
}

// ---------------------------------------------------------------------------
// pass1: per (b,d,chunk): run local recurrence with zero init, store end states
// S layout: [b][d][c][n] (n contiguous). q computed inline (setup fused).
// ---------------------------------------------------------------------------
__global__ void __launch_bounds__(256, 8)
pass1_chunk_end(const float* __restrict__ x,
                const float* __restrict__ damp,
                const float* __restrict__ decay,
                float* __restrict__ S) {
    int d = blockIdx.x * 256 + threadIdx.x;  // 0..1023
    int c = blockIdx.y;                       // 0..NC-1
    int b = blockIdx.z;                       // 0..7

    float q[NH], s[NH];
#pragma unroll
    for (int n = 0; n < NH; n++) {
        int i = d * NH + n;
        q[n] = 1.0f - sigmoidf(damp[i]) * sigmoidf(decay[i]);
        s[n] = 0.0f;
    }

    const float* xp = x + (size_t)c * CHUNK * BD_STRIDE + (size_t)b * D + d;
#pragma unroll 8
    for (int l = 0; l < CHUNK; l++) {
        float xv = xp[(size_t)l * BD_STRIDE];
#pragma unroll
        for (int n = 0; n < NH; n++) s[n] = fmaf(q[n], s[n], xv);
    }

    float* Sp = S + (((size_t)(b * D + d) * NC) + c) * NH;
#pragma unroll
    for (int n = 0; n < NH; n++) Sp[n] = s[n];
}

// ---------------------------------------------------------------------------
// pass2: per (b,d,n): scan NC chunk end-states with factor q^CHUNK; overwrite
// S in-place with carry-IN state for each chunk (state before chunk start).
// ---------------------------------------------------------------------------
__global__ void __launch_bounds__(256)
pass2_scan(float* __restrict__ S,
           const float* __restrict__ damp,
           const float* __restrict__ decay) {
    int gid = blockIdx.x * 256 + threadIdx.x;  // B*D*NH = 131072
    if (gid >= B * D * NH) return;
    int n  = gid & (NH - 1);
    int bd = gid >> 4;            // b*D + d
    int d  = bd & (D - 1);

    int i = d * NH + n;
    float q = 1.0f - sigmoidf(damp[i]) * sigmoidf(decay[i]);
    // qc = q^CHUNK = q^64 via 6 squarings
    float qc = q;
#pragma unroll
    for (int k = 0; k < 6; k++) qc *= qc;

    float s = 0.0f;
    float* Sp = S + (size_t)bd * NC * NH + n;
    for (int c = 0; c < NC; c++) {
        float e = Sp[(size_t)c * NH];   // local end-state of chunk c
        Sp[(size_t)c * NH] = s;         // carry-in for chunk c
        s = fmaf(qc, s, e);             // global end-state of chunk c
    }
}

// ---------------------------------------------------------------------------
// pass3: per (b,d,chunk): re-run recurrence from carry-in, project across
// heads, add residual, relu, nontemporal-write out.
// ---------------------------------------------------------------------------
__global__ void __launch_bounds__(256, 6)
pass3_output(const float* __restrict__ x,
             const float* __restrict__ damp,
             const float* __restrict__ decay,
             const float* __restrict__ ema,
             const float* __restrict__ proj,
             const float* __restrict__ rw,
             const float* __restrict__ carry,  // = S, now holding carry-ins
             float* __restrict__ out) {
    int d = blockIdx.x * 256 + threadIdx.x;
    int c = blockIdx.y;
    int b = blockIdx.z;

    float q[NH], P[NH], s[NH];
    const float* Cp = carry + (((size_t)(b * D + d) * NC) + c) * NH;
#pragma unroll
    for (int n = 0; n < NH; n++) {
        int i = d * NH + n;
        float p = sigmoidf(damp[i]);
        q[n] = 1.0f - p * sigmoidf(decay[i]);
        P[n] = p * ema[i] * proj[i] * 0.25f;  // scaling = (1/16)^0.5
        s[n] = Cp[n];
    }
    float w = rw[d];

    const float* xp = x   + (size_t)c * CHUNK * BD_STRIDE + (size_t)b * D + d;
    float*       op = out + (size_t)c * CHUNK * BD_STRIDE + (size_t)b * D + d;

#pragma unroll 4
    for (int l = 0; l < CHUNK; l++) {
        float xv = xp[(size_t)l * BD_STRIDE];
        float y  = xv * w;  // residual
#pragma unroll
        for (int n = 0; n < NH; n++) {
            s[n] = fmaf(q[n], s[n], xv);
            y    = fmaf(P[n], s[n], y);
        }
        __builtin_nontemporal_store(fmaxf(y, 0.0f), &op[(size_t)l * BD_STRIDE]);
    }
}

// ---------------------------------------------------------------------------
extern "C" void kernel_launch(void* const* d_in, const int* in_sizes, int n_in,
                              void* d_out, int out_size, void* d_ws, size_t ws_size,
                              hipStream_t stream) {
    const float* x     = (const float*)d_in[0];
    const float* damp  = (const float*)d_in[1];
    const float* decay = (const float*)d_in[2];
    const float* ema   = (const float*)d_in[3];
    const float* proj  = (const float*)d_in[4];
    const float* rw    = (const float*)d_in[5];
    float* out = (float*)d_out;

    float* S = (float*)d_ws;   // B*D*NC*NH floats = 33.5 MB

    dim3 grid(D / 256, NC, B);
    pass1_chunk_end<<<grid, 256, 0, stream>>>(x, damp, decay, S);
    pass2_scan<<<(B * D * NH + 255) / 256, 256, 0, stream>>>(S, damp, decay);
    pass3_output<<<grid, 256, 0, stream>>>(x, damp, decay, ema, proj, rw, S, out);
}